// Round 17
// baseline (25728.912 us; speedup 1.0000x reference)
//
#include <hip/hip_runtime.h>
#include <cstdint>
#include <cstddef>

// TransitionDown: FPS(8192 of 32768) + 16-NN + (Linear 64->128, BN, ReLU) + gather/maxpool
// R17: k_fps10 — 256 threads / 4 waves (ONE wave per SIMD). Hypothesis: at 512 thr the
// lockstep phases run at half issue rate (2 waves/SIMD share slots); 4 waves restores
// full rate. Each lane owns 2 cells (seg state in regs, static idx); R15's 1-barrier
// structure; 4-slot fold (2 DPP5 steps). Scan width unchanged (64 lanes/cell).
// FROZEN numerics (R5-PASS, 12x verified): d = fmaf(dz,dz,fmaf(dy,dy,dx*dx)) with
// __fsub_rn subs; fminf(old,d); kNN dot fma-asc + qq/pp fma chains; ties -> lowest
// original index via packed pkd=(oi<<16)|spos.

#define TD_N 32768
#define TD_M 8192

#define ROW_SHR1 0x111
#define ROW_SHR2 0x112
#define ROW_SHR4 0x114
#define ROW_SHR8 0x118
#define ROW_BCAST15 0x142
#define ROW_BCAST31 0x143

#define DPP_MAXF_STEP(V, CTRL)                                                        \
  {                                                                                   \
    float t_ = __int_as_float(__builtin_amdgcn_update_dpp(                            \
        __float_as_int(V), __float_as_int(V), CTRL, 0xF, 0xF, false));                \
    (V) = fmaxf((V), t_);                                                             \
  }
#define DPP_MAXF_64(V)                                                                \
  DPP_MAXF_STEP(V, ROW_SHR1) DPP_MAXF_STEP(V, ROW_SHR2) DPP_MAXF_STEP(V, ROW_SHR4)    \
  DPP_MAXF_STEP(V, ROW_SHR8) DPP_MAXF_STEP(V, ROW_BCAST15) DPP_MAXF_STEP(V, ROW_BCAST31)

#define DPP_MINU_STEP(P, CTRL)                                                        \
  {                                                                                   \
    unsigned t_ = (unsigned)__builtin_amdgcn_update_dpp(                              \
        (int)(P), (int)(P), CTRL, 0xF, 0xF, false);                                   \
    (P) = t_ < (P) ? t_ : (P);                                                        \
  }
#define DPP_MINU_64(P)                                                                \
  DPP_MINU_STEP(P, ROW_SHR1) DPP_MINU_STEP(P, ROW_SHR2) DPP_MINU_STEP(P, ROW_SHR4)    \
  DPP_MINU_STEP(P, ROW_SHR8) DPP_MINU_STEP(P, ROW_BCAST15) DPP_MINU_STEP(P, ROW_BCAST31)

// 5-chain fold step (used only for the 4-slot fold: 2 steps, cheap)
#define DPP5_STEP(KH, KL, X, Y, Z, CTRL)                                              \
  {                                                                                   \
    unsigned nh_ = (unsigned)__builtin_amdgcn_update_dpp((int)(KH), (int)(KH), CTRL, 0xF, 0xF, false); \
    unsigned nl_ = (unsigned)__builtin_amdgcn_update_dpp((int)(KL), (int)(KL), CTRL, 0xF, 0xF, false); \
    int nx_ = __builtin_amdgcn_update_dpp(__float_as_int(X), __float_as_int(X), CTRL, 0xF, 0xF, false); \
    int ny_ = __builtin_amdgcn_update_dpp(__float_as_int(Y), __float_as_int(Y), CTRL, 0xF, 0xF, false); \
    int nz_ = __builtin_amdgcn_update_dpp(__float_as_int(Z), __float_as_int(Z), CTRL, 0xF, 0xF, false); \
    unsigned long long a_ = (((unsigned long long)(KH)) << 32) | (unsigned long long)(KL); \
    unsigned long long b_ = (((unsigned long long)nh_) << 32) | (unsigned long long)nl_;   \
    if (b_ > a_) { KH = nh_; KL = nl_; X = __int_as_float(nx_); Y = __int_as_float(ny_); Z = __int_as_float(nz_); } \
  }

#define HOT_BARRIER()                                           \
  {                                                             \
    asm volatile("s_waitcnt lgkmcnt(0)" ::: "memory");          \
    __builtin_amdgcn_s_barrier();                               \
    __builtin_amdgcn_sched_barrier(0);                          \
    asm volatile("" ::: "memory");                              \
  }

__device__ __forceinline__ float sq3_fma(float a, float b, float c) {
  return fmaf(c, c, fmaf(b, b, __fmul_rn(a, a)));
}

__device__ __forceinline__ int cell_of(float x, float y, float z) {
  int ix = min(7, (int)(x * 8.0f));
  int iy = min(7, (int)(y * 8.0f));
  int iz = min(7, (int)(z * 8.0f));
  return (iz << 6) | (iy << 3) | ix;
}

// ---------------- K0: AoS -> SoA + |p|^2 (fma chain) ----------------
__global__ void k_soa(const float* __restrict__ p1, float* __restrict__ px,
                      float* __restrict__ py, float* __restrict__ pz,
                      float* __restrict__ pp) {
  int i = blockIdx.x * 256 + threadIdx.x;
  float a = p1[i * 3 + 0], b = p1[i * 3 + 1], c = p1[i * 3 + 2];
  px[i] = a; py[i] = b; pz[i] = c;
  pp[i] = sq3_fma(a, b, c);
}

// ---------------- K0b: histogram + prefix -> cell_start, cursor ----------------
__global__ __launch_bounds__(1024) void k_cells(const float* __restrict__ px,
                                                const float* __restrict__ py,
                                                const float* __restrict__ pz,
                                                int* __restrict__ cstart,
                                                int* __restrict__ cursor) {
  __shared__ int hist[512];
  __shared__ int wsum[16];
  int t = threadIdx.x;
  if (t < 512) hist[t] = 0;
  __syncthreads();
  for (int i = t; i < TD_N; i += 1024)
    atomicAdd(&hist[cell_of(px[i], py[i], pz[i])], 1);
  __syncthreads();
  int v = (t < 512) ? hist[t] : 0;
  int lane = t & 63, w = t >> 6;
  int s = v;
#pragma unroll
  for (int off = 1; off < 64; off <<= 1) {
    int o = __shfl_up(s, off);
    if (lane >= off) s += o;
  }
  if (lane == 63) wsum[w] = s;
  __syncthreads();
  if (t == 0) { int a = 0; for (int i = 0; i < 16; ++i) { int x = wsum[i]; wsum[i] = a; a += x; } }
  __syncthreads();
  int ex = s - v + wsum[w];
  if (t < 512) { cstart[t] = ex; cursor[t] = ex; }
  if (t == 0) cstart[512] = TD_N;
}

// ---------------- K0c: scatter into cell-sorted packed float4 ----------------
// Atomic order nondeterministic, but FPS outputs are order-invariant (elementwise
// min_d updates + unique-original-index tie-breaks).
__global__ __launch_bounds__(256) void k_scatter(const float* __restrict__ px,
                                                 const float* __restrict__ py,
                                                 const float* __restrict__ pz,
                                                 int* __restrict__ cursor,
                                                 float4* __restrict__ pk) {
  int i = blockIdx.x * 256 + threadIdx.x;
  float X = px[i], Y = py[i], Z = pz[i];
  int c = cell_of(X, Y, Z);
  int pos = atomicAdd(&cursor[c], 1);
  pk[pos] = make_float4(X, Y, Z, __int_as_float(i));
}

// ---------------- K1: h = x@W + b, + per-block BN partial sums ----------------
__global__ __launch_bounds__(256) void k_mlp(const float* __restrict__ x,
                                             const float* __restrict__ W,
                                             const float* __restrict__ bias,
                                             float* __restrict__ h,
                                             float* __restrict__ part) {
  __shared__ float Wl[64 * 128];
  __shared__ float pl[4][2][128];
  int t = threadIdx.x;
#pragma unroll
  for (int i = 0; i < 8; ++i) {
    int f4 = t + i * 256;
    ((float4*)Wl)[f4] = ((const float4*)W)[f4];
  }
  __syncthreads();

  int rg = t >> 4;
  int ch = (t & 15) * 8;
  int row0 = blockIdx.x * 64 + rg * 4;

  float acc[4][8];
#pragma unroll
  for (int r = 0; r < 4; ++r)
#pragma unroll
    for (int c = 0; c < 8; ++c) acc[r][c] = 0.f;

  const float* xrow = x + (size_t)row0 * 64;
#pragma unroll 4
  for (int kc = 0; kc < 16; ++kc) {
    float xv[4][4];
#pragma unroll
    for (int r = 0; r < 4; ++r) {
      float4 t4 = *(const float4*)(xrow + r * 64 + kc * 4);
      xv[r][0] = t4.x; xv[r][1] = t4.y; xv[r][2] = t4.z; xv[r][3] = t4.w;
    }
#pragma unroll
    for (int kk = 0; kk < 4; ++kk) {
      int k = kc * 4 + kk;
      float4 wa = *(const float4*)&Wl[k * 128 + ch];
      float4 wb = *(const float4*)&Wl[k * 128 + ch + 4];
      float wv[8] = {wa.x, wa.y, wa.z, wa.w, wb.x, wb.y, wb.z, wb.w};
#pragma unroll
      for (int r = 0; r < 4; ++r)
#pragma unroll
        for (int c = 0; c < 8; ++c) acc[r][c] = fmaf(xv[r][kk], wv[c], acc[r][c]);
    }
  }

  float bv[8];
#pragma unroll
  for (int c = 0; c < 8; ++c) bv[c] = bias[ch + c];
  float s[8], q2[8];
#pragma unroll
  for (int c = 0; c < 8; ++c) { s[c] = 0.f; q2[c] = 0.f; }
#pragma unroll
  for (int r = 0; r < 4; ++r) {
    float hv[8];
#pragma unroll
    for (int c = 0; c < 8; ++c) hv[c] = acc[r][c] + bv[c];
    *(float4*)&h[(size_t)(row0 + r) * 128 + ch] = make_float4(hv[0], hv[1], hv[2], hv[3]);
    *(float4*)&h[(size_t)(row0 + r) * 128 + ch + 4] = make_float4(hv[4], hv[5], hv[6], hv[7]);
#pragma unroll
    for (int c = 0; c < 8; ++c) { s[c] += hv[c]; q2[c] = fmaf(hv[c], hv[c], q2[c]); }
  }
#pragma unroll
  for (int off = 16; off <= 32; off <<= 1) {
#pragma unroll
    for (int c = 0; c < 8; ++c) {
      s[c] += __shfl_xor(s[c], off);
      q2[c] += __shfl_xor(q2[c], off);
    }
  }
  int wv_ = t >> 6;
  if ((t & 63) < 16) {
#pragma unroll
    for (int c = 0; c < 8; ++c) { pl[wv_][0][ch + c] = s[c]; pl[wv_][1][ch + c] = q2[c]; }
  }
  __syncthreads();
  if (t < 128) {
    float S = 0.f, Q = 0.f;
#pragma unroll
    for (int w = 0; w < 4; ++w) { S += pl[w][0][t]; Q += pl[w][1][t]; }
    part[(size_t)blockIdx.x * 256 + t] = S;
    part[(size_t)blockIdx.x * 256 + 128 + t] = Q;
  }
}

// ---------------- K2: finalize BN -> scale/shift ----------------
__global__ void k_bn(const float* __restrict__ part, const float* __restrict__ gamma,
                     const float* __restrict__ beta, float* __restrict__ ss) {
  int t = threadIdx.x;  // 128
  float S = 0.f, Q = 0.f;
  for (int b = 0; b < 512; ++b) {
    S += part[(size_t)b * 256 + t];
    Q += part[(size_t)b * 256 + 128 + t];
  }
  float mean = S * (1.0f / 32768.0f);
  float var = Q * (1.0f / 32768.0f) - mean * mean;
  var = fmaxf(var, 0.0f);
  float inv = 1.0f / sqrtf(var + 1e-5f);
  float sc = gamma[t] * inv;
  ss[t] = sc;
  ss[128 + t] = beta[t] - mean * sc;
}

// ---------------- K3: FPS — 256 thr / 4 waves, 2 cells/lane, 1 barrier/iter ----------------
__global__ __launch_bounds__(256) void k_fps10(const float4* __restrict__ pk,
                                               const int* __restrict__ cstart,
                                               const float* __restrict__ p1,
                                               float* __restrict__ p2) {
  extern __shared__ float lds[];
  float* md = lds;                              // [32768]
  unsigned* wc = (unsigned*)(lds + 32768);      // [2][4][8] u32 (5 used)
  float* winbuf = lds + 32768 + 64;             // [512][3]

  int t = threadIdx.x;
  int lane = t & 63, w = t >> 6;   // w in 0..3

  for (int i = t; i < TD_N; i += 256) md[i] = 1e10f;

  // my 2 cells: c0 = 2t, c1 = 2t+1 (wave w owns cells 128w..128w+127)
  int st0 = min(max(cstart[2 * t], 0), TD_N);
  int en0 = min(max(cstart[2 * t + 1], 0), TD_N); en0 = max(en0, st0);
  int st1 = en0;  // contiguous: cstart[2t+1] clamped
  int en1 = min(max(cstart[2 * t + 2], 0), TD_N); en1 = max(en1, st1);

  float bxl0 = 1e30f, bxh0 = -1e30f, byl0 = 1e30f, byh0 = -1e30f, bzl0 = 1e30f, bzh0 = -1e30f;
  for (int p = st0; p < en0; ++p) {
    float4 v = pk[p];
    bxl0 = fminf(bxl0, v.x); bxh0 = fmaxf(bxh0, v.x);
    byl0 = fminf(byl0, v.y); byh0 = fmaxf(byh0, v.y);
    bzl0 = fminf(bzl0, v.z); bzh0 = fmaxf(bzh0, v.z);
  }
  float bxl1 = 1e30f, bxh1 = -1e30f, byl1 = 1e30f, byh1 = -1e30f, bzl1 = 1e30f, bzh1 = -1e30f;
  for (int p = st1; p < en1; ++p) {
    float4 v = pk[p];
    bxl1 = fminf(bxl1, v.x); bxh1 = fmaxf(bxh1, v.x);
    byl1 = fminf(byl1, v.y); byh1 = fmaxf(byh1, v.y);
    bzl1 = fminf(bzl1, v.z); bzh1 = fmaxf(bzh1, v.z);
  }
  float sv0 = (st0 < en0) ? 1e10f : -1.0f;  unsigned sp0 = 0xFFFFFFFFu;
  float sx0 = 0.f, sy0 = 0.f, sz0 = 0.f;
  float sv1 = (st1 < en1) ? 1e10f : -1.0f;  unsigned sp1 = 0xFFFFFFFFu;
  float sx1 = 0.f, sy1 = 0.f, sz1 = 0.f;

  float qx = p1[0], qy = p1[1], qz = p1[2];
  if (t == 0) { p2[0] = qx; p2[1] = qy; p2[2] = qz; }
  __syncthreads();

  for (int it = 1; it < TD_M; ++it) {
    // ---- prune both cells (registers only) ----
    float d0x = fmaxf(0.f, fmaxf(__fsub_rn(bxl0, qx), __fsub_rn(qx, bxh0)));
    float d0y = fmaxf(0.f, fmaxf(__fsub_rn(byl0, qy), __fsub_rn(qy, byh0)));
    float d0z = fmaxf(0.f, fmaxf(__fsub_rn(bzl0, qz), __fsub_rn(qz, bzh0)));
    float lb0 = d0x * d0x + d0y * d0y + d0z * d0z;
    bool dirty0 = !(lb0 * 0.99999f >= sv0);  // safe-skip margin >> chain err ~1e-6
    float d1x = fmaxf(0.f, fmaxf(__fsub_rn(bxl1, qx), __fsub_rn(qx, bxh1)));
    float d1y = fmaxf(0.f, fmaxf(__fsub_rn(byl1, qy), __fsub_rn(qy, byh1)));
    float d1z = fmaxf(0.f, fmaxf(__fsub_rn(bzl1, qz), __fsub_rn(qz, bzh1)));
    float lb1 = d1x * d1x + d1y * d1y + d1z * d1z;
    bool dirty1 = !(lb1 * 0.99999f >= sv1);

    // ---- scan dirty cells: walk bit0 mask then bit1 mask (static seg indices) ----
#define SCAN_WALK(MASK, STV, ENV, SVV, SPV, SXV, SYV, SZV)                            \
    {                                                                                 \
      unsigned long long mm_ = (MASK);                                                \
      while (mm_) {                                                                   \
        int cl_ = (int)__builtin_ctzll(mm_); mm_ &= mm_ - 1;                          \
        int st_ = __builtin_amdgcn_readlane((STV), cl_);                              \
        int en_ = __builtin_amdgcn_readlane((ENV), cl_);                              \
        float bv_ = -2.0f; unsigned bp_ = 0xFFFFFFFFu;                                \
        float bxv_ = 0.f, byv_ = 0.f, bzv_ = 0.f;                                     \
        for (int p0_ = st_; p0_ < en_; p0_ += 64) {                                   \
          int p_ = p0_ + lane;                                                        \
          if (p_ < en_) {                                                             \
            float4 v_ = pk[p_];                                                       \
            float dx_ = __fsub_rn(v_.x, qx);                                          \
            float dy_ = __fsub_rn(v_.y, qy);                                          \
            float dz_ = __fsub_rn(v_.z, qz);                                          \
            float d2_ = fmaf(dz_, dz_, fmaf(dy_, dy_, __fmul_rn(dx_, dx_)));          \
            float nm_ = fminf(md[p_], d2_);                                           \
            md[p_] = nm_;                                                             \
            unsigned pkd_ = (((unsigned)__float_as_int(v_.w)) << 16) | (unsigned)p_;  \
            if (nm_ > bv_ || (nm_ == bv_ && pkd_ < bp_)) {                            \
              bv_ = nm_; bp_ = pkd_; bxv_ = v_.x; byv_ = v_.y; bzv_ = v_.z;           \
            }                                                                         \
          }                                                                           \
        }                                                                             \
        float mv_ = bv_;                                                              \
        DPP_MAXF_64(mv_)                                                              \
        float rmax_ = __int_as_float(__builtin_amdgcn_readlane(__float_as_int(mv_), 63)); \
        unsigned mp_ = (bv_ == rmax_) ? bp_ : 0xFFFFFFFFu;                            \
        DPP_MINU_64(mp_)                                                              \
        unsigned rpkd_ = (unsigned)__builtin_amdgcn_readlane((int)mp_, 63);           \
        unsigned long long wm_ = __ballot(bv_ == rmax_ && bp_ == rpkd_);              \
        int wl_ = (int)__builtin_ctzll(wm_);                                          \
        float wx_ = __int_as_float(__builtin_amdgcn_readlane(__float_as_int(bxv_), wl_)); \
        float wy_ = __int_as_float(__builtin_amdgcn_readlane(__float_as_int(byv_), wl_)); \
        float wz_ = __int_as_float(__builtin_amdgcn_readlane(__float_as_int(bzv_), wl_)); \
        if (lane == cl_) { SVV = rmax_; SPV = rpkd_; SXV = wx_; SYV = wy_; SZV = wz_; } \
      }                                                                               \
    }
    SCAN_WALK(__ballot(dirty0), st0, en0, sv0, sp0, sx0, sy0, sz0)
    SCAN_WALK(__ballot(dirty1), st1, en1, sv1, sp1, sx1, sy1, sz1)
#undef SCAN_WALK

    // ---- wave candidate: lane-local 2-cell fold, then slim two-phase ----
    {
      float lv; unsigned lp; float lx, ly, lz;
      if (sv1 > sv0 || (sv1 == sv0 && sp1 < sp0)) {
        lv = sv1; lp = sp1; lx = sx1; ly = sy1; lz = sz1;
      } else {
        lv = sv0; lp = sp0; lx = sx0; ly = sy0; lz = sz0;
      }
      float mv = lv;
      DPP_MAXF_64(mv)
      float rmax = __int_as_float(__builtin_amdgcn_readlane(__float_as_int(mv), 63));
      unsigned mp = (lv == rmax) ? lp : 0xFFFFFFFFu;
      DPP_MINU_64(mp)
      unsigned rpkd = (unsigned)__builtin_amdgcn_readlane((int)mp, 63);
      unsigned long long wm = __ballot(lv == rmax && lp == rpkd);
      int wl = (int)__builtin_ctzll(wm);
      float wx = __int_as_float(__builtin_amdgcn_readlane(__float_as_int(lx), wl));
      float wy = __int_as_float(__builtin_amdgcn_readlane(__float_as_int(ly), wl));
      float wz = __int_as_float(__builtin_amdgcn_readlane(__float_as_int(lz), wl));
      if (lane == 63) {
        unsigned* slot = &wc[((it & 1) << 5) + (w << 3)];
        slot[0] = (rmax < 0.f) ? 0u : __float_as_uint(rmax);  // empty wave -> key 0
        slot[1] = ~rpkd;
        slot[2] = __float_as_uint(wx); slot[3] = __float_as_uint(wy); slot[4] = __float_as_uint(wz);
      }
    }
    HOT_BARRIER()

    // ---- all waves: fold 4 slots (lanes 0..3), 2 DPP5 steps, winner in lane 3 ----
    {
      unsigned gh = 0u, gl = 0u; float gx = 0.f, gy = 0.f, gz = 0.f;
      if (lane < 4) {
        unsigned* slot = &wc[((it & 1) << 5) + (lane << 3)];
        gh = slot[0]; gl = slot[1];
        gx = __uint_as_float(slot[2]); gy = __uint_as_float(slot[3]); gz = __uint_as_float(slot[4]);
      }
      DPP5_STEP(gh, gl, gx, gy, gz, ROW_SHR1)
      DPP5_STEP(gh, gl, gx, gy, gz, ROW_SHR2)
      qx = __int_as_float(__builtin_amdgcn_readlane(__float_as_int(gx), 3));
      qy = __int_as_float(__builtin_amdgcn_readlane(__float_as_int(gy), 3));
      qz = __int_as_float(__builtin_amdgcn_readlane(__float_as_int(gz), 3));
    }
    if (t == 0) {
      int s0 = (it & 511) * 3;
      winbuf[s0 + 0] = qx; winbuf[s0 + 1] = qy; winbuf[s0 + 2] = qz;
    }

    // ---- flush p2 every 512 iterations (256 threads -> 2 entries each) ----
    if ((it & 511) == 511) {
      __syncthreads();
#pragma unroll
      for (int rep = 0; rep < 2; ++rep) {
        int j = it - 511 + t + rep * 256;
        if (j >= 1 && j <= it) {
          int s0 = (j & 511) * 3;
          p2[(size_t)j * 3 + 0] = winbuf[s0 + 0];
          p2[(size_t)j * 3 + 1] = winbuf[s0 + 1];
          p2[(size_t)j * 3 + 2] = winbuf[s0 + 2];
        }
      }
      __syncthreads();
    }
  }
}

// ---------------- K4: 16-NN — expanded f32, all-FMA chains (frozen from R5) ----------------
__device__ __forceinline__ unsigned long long shfl_xor_u64(unsigned long long v, int m) {
  unsigned lo = __shfl_xor((unsigned)v, m);
  unsigned hi = __shfl_xor((unsigned)(v >> 32), m);
  return ((unsigned long long)hi << 32) | lo;
}

__global__ __launch_bounds__(256) void k_knn(const float* __restrict__ px,
                                             const float* __restrict__ py,
                                             const float* __restrict__ pz,
                                             const float* __restrict__ pp,
                                             const float* __restrict__ p2,
                                             int* __restrict__ nb) {
  __shared__ unsigned long long mq[4][16][64];
  int wid = threadIdx.x >> 6, lane = threadIdx.x & 63;
  int q = blockIdx.x * 4 + wid;
  float qx = p2[(size_t)q * 3 + 0], qy = p2[(size_t)q * 3 + 1], qz = p2[(size_t)q * 3 + 2];
  float qq = sq3_fma(qx, qy, qz);

  unsigned long long sl[16];
#pragma unroll
  for (int s = 0; s < 16; ++s) sl[s] = ~0ULL;

#pragma unroll 2
  for (int c = 0; c < 512; ++c) {
    int i = c * 64 + lane;
    float X = px[i], Y = py[i], Z = pz[i], P = pp[i];
    float dot = fmaf(qz, Z, fmaf(qy, Y, __fmul_rn(qx, X)));       // fma-ascending
    float d2 = __fadd_rn(__fsub_rn(qq, __fadd_rn(dot, dot)), P);  // (qq - 2*dot) + pp
    unsigned u = __float_as_uint(d2);
    u ^= ((unsigned)(((int)u) >> 31)) | 0x80000000u;
    unsigned long long key = ((unsigned long long)u << 32) | (unsigned)i;
#pragma unroll
    for (int s = 0; s < 16; ++s) {
      unsigned long long lo = key < sl[s] ? key : sl[s];
      unsigned long long hi = key < sl[s] ? sl[s] : key;
      sl[s] = lo;
      key = hi;
    }
  }
#pragma unroll
  for (int s = 0; s < 16; ++s) mq[wid][s][lane] = sl[s];
  int head = 0;
  for (int r = 0; r < 16; ++r) {
    int hh = head < 16 ? head : 15;
    unsigned long long kk = mq[wid][hh][lane];
    if (head >= 16) kk = ~0ULL;
    unsigned long long v = kk;
#pragma unroll
    for (int off = 32; off; off >>= 1) {
      unsigned long long o = shfl_xor_u64(v, off);
      if (o < v) v = o;
    }
    if (kk == v) head++;
    if (lane == 0) nb[(size_t)q * 16 + r] = (int)(v & 0xffffffffULL);
  }
}

// ---------------- K5: gather + affine + relu + maxpool ----------------
__global__ __launch_bounds__(256) void k_gather(const float* __restrict__ h,
                                                const float* __restrict__ ss,
                                                const int* __restrict__ nb,
                                                float* __restrict__ y) {
  int t = threadIdx.x;
  int q = blockIdx.x * 2 + (t >> 7);
  int ch = t & 127;
  float sc = ss[ch], sh = ss[128 + ch];
  float m = -3.4e38f;
#pragma unroll
  for (int k = 0; k < 16; ++k) {
    int n = nb[(size_t)q * 16 + k];
    float v = h[(size_t)n * 128 + ch];
    m = fmaxf(m, fmaf(v, sc, sh));
  }
  y[(size_t)q * 128 + ch] = fmaxf(m, 0.0f);
}

extern "C" void kernel_launch(void* const* d_in, const int* in_sizes, int n_in,
                              void* d_out, int out_size, void* d_ws, size_t ws_size,
                              hipStream_t stream) {
  (void)in_sizes; (void)n_in; (void)out_size; (void)ws_size;
  const float* x = (const float*)d_in[0];
  const float* p1 = (const float*)d_in[1];
  const float* W = (const float*)d_in[2];
  const float* bias = (const float*)d_in[3];
  const float* gamma = (const float*)d_in[4];
  const float* beta = (const float*)d_in[5];

  float* out = (float*)d_out;
  float* y = out;                    // (8192,128)
  float* p2 = out + 1048576;         // (8192,3)

  // ws layout — identical footprint to R6/R8-proven:
  float* w = (float*)d_ws;
  float* h = w;                      // 4194304
  float* part = w + 4194304;         // 131072
  float* ss = w + 4325376;           // 256
  float* px = w + 4325632;           // 32768
  float* py = w + 4358400;
  float* pz = w + 4391168;
  float* pp = w + 4423936;
  int* nb = (int*)(w + 4456704);     // 8192*16 ints -> end 4489472 floats

  // FPS scratch in d_out's y-region (overwritten by k_gather at the very end):
  float4* pk = (float4*)y;           // 32768 float4 = 131072 floats
  int* cstart = (int*)(y + 131072);  // 513
  int* cursor = (int*)(y + 131648);  // 512   (end 132160 << 1048576)

  // md 32768 + wc 64 + winbuf 1536 = 34368 floats = 137472 B
  const int fps_lds = 34368 * 4;
  hipFuncSetAttribute((const void*)k_fps10, hipFuncAttributeMaxDynamicSharedMemorySize, fps_lds);

  k_soa<<<128, 256, 0, stream>>>(p1, px, py, pz, pp);
  k_cells<<<1, 1024, 0, stream>>>(px, py, pz, cstart, cursor);
  k_scatter<<<128, 256, 0, stream>>>(px, py, pz, cursor, pk);
  k_mlp<<<512, 256, 0, stream>>>(x, W, bias, h, part);
  k_bn<<<1, 128, 0, stream>>>(part, gamma, beta, ss);
  k_fps10<<<1, 256, fps_lds, stream>>>(pk, cstart, p1, p2);
  k_knn<<<2048, 256, 0, stream>>>(px, py, pz, pp, p2, nb);
  k_gather<<<4096, 256, 0, stream>>>(h, ss, nb, y);
}

// Round 18
// 13299.496 us; speedup vs baseline: 1.9346x; 1.9346x over previous
//
#include <hip/hip_runtime.h>
#include <cstdint>
#include <cstddef>

// TransitionDown: FPS(8192 of 32768) + 16-NN + (Linear 64->128, BN, ReLU) + gather/maxpool
// R18: k_fps11 = R15's k_fps8 (best, 19.3ms steady) with ONE change: hashed cell
// ownership. lane l of wave w owns c=(iz<<6)|(iy<<3)|ix, iy=l&7, iz=l>>3,
// ix=(w-3iy-5iz)&7 — bijective, 64 cells/wave; a 3x3x3 dirty neighborhood spreads
// across waves with max multiplicity 4 (vs 9 for R15's iz-slabs) at ZERO runtime cost
// (R16 proved redistribution worth ~800cyc but paid 2 barriers; this pays nothing).
// FROZEN numerics (R5-PASS, 13x verified): d = fmaf(dz,dz,fmaf(dy,dy,dx*dx)) with
// __fsub_rn subs; fminf(old,d); kNN dot fma-asc + qq/pp fma chains; ties -> lowest
// original index via packed pkd=(oi<<16)|spos.

#define TD_N 32768
#define TD_M 8192

#define ROW_SHR1 0x111
#define ROW_SHR2 0x112
#define ROW_SHR4 0x114
#define ROW_SHR8 0x118
#define ROW_BCAST15 0x142
#define ROW_BCAST31 0x143

#define DPP_MAXF_STEP(V, CTRL)                                                        \
  {                                                                                   \
    float t_ = __int_as_float(__builtin_amdgcn_update_dpp(                            \
        __float_as_int(V), __float_as_int(V), CTRL, 0xF, 0xF, false));                \
    (V) = fmaxf((V), t_);                                                             \
  }
#define DPP_MAXF_64(V)                                                                \
  DPP_MAXF_STEP(V, ROW_SHR1) DPP_MAXF_STEP(V, ROW_SHR2) DPP_MAXF_STEP(V, ROW_SHR4)    \
  DPP_MAXF_STEP(V, ROW_SHR8) DPP_MAXF_STEP(V, ROW_BCAST15) DPP_MAXF_STEP(V, ROW_BCAST31)

#define DPP_MINU_STEP(P, CTRL)                                                        \
  {                                                                                   \
    unsigned t_ = (unsigned)__builtin_amdgcn_update_dpp(                              \
        (int)(P), (int)(P), CTRL, 0xF, 0xF, false);                                   \
    (P) = t_ < (P) ? t_ : (P);                                                        \
  }
#define DPP_MINU_64(P)                                                                \
  DPP_MINU_STEP(P, ROW_SHR1) DPP_MINU_STEP(P, ROW_SHR2) DPP_MINU_STEP(P, ROW_SHR4)    \
  DPP_MINU_STEP(P, ROW_SHR8) DPP_MINU_STEP(P, ROW_BCAST15) DPP_MINU_STEP(P, ROW_BCAST31)

// 5-chain fold step (used only for the 8-slot fold: 3 steps, cheap)
#define DPP5_STEP(KH, KL, X, Y, Z, CTRL)                                              \
  {                                                                                   \
    unsigned nh_ = (unsigned)__builtin_amdgcn_update_dpp((int)(KH), (int)(KH), CTRL, 0xF, 0xF, false); \
    unsigned nl_ = (unsigned)__builtin_amdgcn_update_dpp((int)(KL), (int)(KL), CTRL, 0xF, 0xF, false); \
    int nx_ = __builtin_amdgcn_update_dpp(__float_as_int(X), __float_as_int(X), CTRL, 0xF, 0xF, false); \
    int ny_ = __builtin_amdgcn_update_dpp(__float_as_int(Y), __float_as_int(Y), CTRL, 0xF, 0xF, false); \
    int nz_ = __builtin_amdgcn_update_dpp(__float_as_int(Z), __float_as_int(Z), CTRL, 0xF, 0xF, false); \
    unsigned long long a_ = (((unsigned long long)(KH)) << 32) | (unsigned long long)(KL); \
    unsigned long long b_ = (((unsigned long long)nh_) << 32) | (unsigned long long)nl_;   \
    if (b_ > a_) { KH = nh_; KL = nl_; X = __int_as_float(nx_); Y = __int_as_float(ny_); Z = __int_as_float(nz_); } \
  }

#define HOT_BARRIER()                                           \
  {                                                             \
    asm volatile("s_waitcnt lgkmcnt(0)" ::: "memory");          \
    __builtin_amdgcn_s_barrier();                               \
    __builtin_amdgcn_sched_barrier(0);                          \
    asm volatile("" ::: "memory");                              \
  }

__device__ __forceinline__ float sq3_fma(float a, float b, float c) {
  return fmaf(c, c, fmaf(b, b, __fmul_rn(a, a)));
}

__device__ __forceinline__ int cell_of(float x, float y, float z) {
  int ix = min(7, (int)(x * 8.0f));
  int iy = min(7, (int)(y * 8.0f));
  int iz = min(7, (int)(z * 8.0f));
  return (iz << 6) | (iy << 3) | ix;
}

// ---------------- K0: AoS -> SoA + |p|^2 (fma chain) ----------------
__global__ void k_soa(const float* __restrict__ p1, float* __restrict__ px,
                      float* __restrict__ py, float* __restrict__ pz,
                      float* __restrict__ pp) {
  int i = blockIdx.x * 256 + threadIdx.x;
  float a = p1[i * 3 + 0], b = p1[i * 3 + 1], c = p1[i * 3 + 2];
  px[i] = a; py[i] = b; pz[i] = c;
  pp[i] = sq3_fma(a, b, c);
}

// ---------------- K0b: histogram + prefix -> cell_start, cursor ----------------
__global__ __launch_bounds__(1024) void k_cells(const float* __restrict__ px,
                                                const float* __restrict__ py,
                                                const float* __restrict__ pz,
                                                int* __restrict__ cstart,
                                                int* __restrict__ cursor) {
  __shared__ int hist[512];
  __shared__ int wsum[16];
  int t = threadIdx.x;
  if (t < 512) hist[t] = 0;
  __syncthreads();
  for (int i = t; i < TD_N; i += 1024)
    atomicAdd(&hist[cell_of(px[i], py[i], pz[i])], 1);
  __syncthreads();
  int v = (t < 512) ? hist[t] : 0;
  int lane = t & 63, w = t >> 6;
  int s = v;
#pragma unroll
  for (int off = 1; off < 64; off <<= 1) {
    int o = __shfl_up(s, off);
    if (lane >= off) s += o;
  }
  if (lane == 63) wsum[w] = s;
  __syncthreads();
  if (t == 0) { int a = 0; for (int i = 0; i < 16; ++i) { int x = wsum[i]; wsum[i] = a; a += x; } }
  __syncthreads();
  int ex = s - v + wsum[w];
  if (t < 512) { cstart[t] = ex; cursor[t] = ex; }
  if (t == 0) cstart[512] = TD_N;
}

// ---------------- K0c: scatter into cell-sorted packed float4 ----------------
// Atomic order nondeterministic, but FPS outputs are order-invariant (elementwise
// min_d updates + unique-original-index tie-breaks).
__global__ __launch_bounds__(256) void k_scatter(const float* __restrict__ px,
                                                 const float* __restrict__ py,
                                                 const float* __restrict__ pz,
                                                 int* __restrict__ cursor,
                                                 float4* __restrict__ pk) {
  int i = blockIdx.x * 256 + threadIdx.x;
  float X = px[i], Y = py[i], Z = pz[i];
  int c = cell_of(X, Y, Z);
  int pos = atomicAdd(&cursor[c], 1);
  pk[pos] = make_float4(X, Y, Z, __int_as_float(i));
}

// ---------------- K1: h = x@W + b, + per-block BN partial sums ----------------
__global__ __launch_bounds__(256) void k_mlp(const float* __restrict__ x,
                                             const float* __restrict__ W,
                                             const float* __restrict__ bias,
                                             float* __restrict__ h,
                                             float* __restrict__ part) {
  __shared__ float Wl[64 * 128];
  __shared__ float pl[4][2][128];
  int t = threadIdx.x;
#pragma unroll
  for (int i = 0; i < 8; ++i) {
    int f4 = t + i * 256;
    ((float4*)Wl)[f4] = ((const float4*)W)[f4];
  }
  __syncthreads();

  int rg = t >> 4;
  int ch = (t & 15) * 8;
  int row0 = blockIdx.x * 64 + rg * 4;

  float acc[4][8];
#pragma unroll
  for (int r = 0; r < 4; ++r)
#pragma unroll
    for (int c = 0; c < 8; ++c) acc[r][c] = 0.f;

  const float* xrow = x + (size_t)row0 * 64;
#pragma unroll 4
  for (int kc = 0; kc < 16; ++kc) {
    float xv[4][4];
#pragma unroll
    for (int r = 0; r < 4; ++r) {
      float4 t4 = *(const float4*)(xrow + r * 64 + kc * 4);
      xv[r][0] = t4.x; xv[r][1] = t4.y; xv[r][2] = t4.z; xv[r][3] = t4.w;
    }
#pragma unroll
    for (int kk = 0; kk < 4; ++kk) {
      int k = kc * 4 + kk;
      float4 wa = *(const float4*)&Wl[k * 128 + ch];
      float4 wb = *(const float4*)&Wl[k * 128 + ch + 4];
      float wv[8] = {wa.x, wa.y, wa.z, wa.w, wb.x, wb.y, wb.z, wb.w};
#pragma unroll
      for (int r = 0; r < 4; ++r)
#pragma unroll
        for (int c = 0; c < 8; ++c) acc[r][c] = fmaf(xv[r][kk], wv[c], acc[r][c]);
    }
  }

  float bv[8];
#pragma unroll
  for (int c = 0; c < 8; ++c) bv[c] = bias[ch + c];
  float s[8], q2[8];
#pragma unroll
  for (int c = 0; c < 8; ++c) { s[c] = 0.f; q2[c] = 0.f; }
#pragma unroll
  for (int r = 0; r < 4; ++r) {
    float hv[8];
#pragma unroll
    for (int c = 0; c < 8; ++c) hv[c] = acc[r][c] + bv[c];
    *(float4*)&h[(size_t)(row0 + r) * 128 + ch] = make_float4(hv[0], hv[1], hv[2], hv[3]);
    *(float4*)&h[(size_t)(row0 + r) * 128 + ch + 4] = make_float4(hv[4], hv[5], hv[6], hv[7]);
#pragma unroll
    for (int c = 0; c < 8; ++c) { s[c] += hv[c]; q2[c] = fmaf(hv[c], hv[c], q2[c]); }
  }
#pragma unroll
  for (int off = 16; off <= 32; off <<= 1) {
#pragma unroll
    for (int c = 0; c < 8; ++c) {
      s[c] += __shfl_xor(s[c], off);
      q2[c] += __shfl_xor(q2[c], off);
    }
  }
  int wv_ = t >> 6;
  if ((t & 63) < 16) {
#pragma unroll
    for (int c = 0; c < 8; ++c) { pl[wv_][0][ch + c] = s[c]; pl[wv_][1][ch + c] = q2[c]; }
  }
  __syncthreads();
  if (t < 128) {
    float S = 0.f, Q = 0.f;
#pragma unroll
    for (int w = 0; w < 4; ++w) { S += pl[w][0][t]; Q += pl[w][1][t]; }
    part[(size_t)blockIdx.x * 256 + t] = S;
    part[(size_t)blockIdx.x * 256 + 128 + t] = Q;
  }
}

// ---------------- K2: finalize BN -> scale/shift ----------------
__global__ void k_bn(const float* __restrict__ part, const float* __restrict__ gamma,
                     const float* __restrict__ beta, float* __restrict__ ss) {
  int t = threadIdx.x;  // 128
  float S = 0.f, Q = 0.f;
  for (int b = 0; b < 512; ++b) {
    S += part[(size_t)b * 256 + t];
    Q += part[(size_t)b * 256 + 128 + t];
  }
  float mean = S * (1.0f / 32768.0f);
  float var = Q * (1.0f / 32768.0f) - mean * mean;
  var = fmaxf(var, 0.0f);
  float inv = 1.0f / sqrtf(var + 1e-5f);
  float sc = gamma[t] * inv;
  ss[t] = sc;
  ss[128 + t] = beta[t] - mean * sc;
}

// ---------------- K3: FPS — 512 thr, hashed cell ownership, slim reduces ----------------
__global__ __launch_bounds__(512) void k_fps11(const float4* __restrict__ pk,
                                               const int* __restrict__ cstart,
                                               const float* __restrict__ p1,
                                               float* __restrict__ p2) {
  extern __shared__ float lds[];
  float* md = lds;                              // [32768]
  unsigned* wc = (unsigned*)(lds + 32768);      // [2][8][8] u32 (5 used)
  float* winbuf = lds + 32768 + 128;            // [512][3]

  int t = threadIdx.x;
  int lane = t & 63, w = t >> 6;

  for (int i = t; i < TD_N; i += 512) md[i] = 1e10f;

  // R18 change: hashed ownership. lane l of wave w owns cell with
  // iy=l&7, iz=l>>3, ix=(w-3iy-5iz)&7 -> 3x3x3 neighborhoods spread over
  // owner waves with max multiplicity 4 (vs 9 for iz-slab ownership).
  int oiy = lane & 7, oiz = lane >> 3;
  int oix = (w - 3 * oiy - 5 * oiz) & 7;
  int myc = (oiz << 6) | (oiy << 3) | oix;
  int stR = cstart[myc], enR = cstart[myc + 1];
  stR = min(max(stR, 0), TD_N);
  enR = min(max(enR, stR), TD_N);
  float bx0 = 1e30f, bx1 = -1e30f, by0 = 1e30f, by1 = -1e30f, bz0 = 1e30f, bz1 = -1e30f;
  for (int p = stR; p < enR; ++p) {
    float4 v = pk[p];
    bx0 = fminf(bx0, v.x); bx1 = fmaxf(bx1, v.x);
    by0 = fminf(by0, v.y); by1 = fmaxf(by1, v.y);
    bz0 = fminf(bz0, v.z); bz1 = fmaxf(bz1, v.z);
  }
  bool nonempty = (stR < enR);
  float sv = nonempty ? 1e10f : -1.0f;  // seg max value
  unsigned spk = 0xFFFFFFFFu;           // seg argmax pkd
  float sx = 0.f, sy = 0.f, sz = 0.f;   // seg argmax coords
  float qx = p1[0], qy = p1[1], qz = p1[2];
  if (t == 0) { p2[0] = qx; p2[1] = qy; p2[2] = qz; }
  __syncthreads();

  for (int it = 1; it < TD_M; ++it) {
    // ---- prune my cell (registers only) ----
    float dxm = fmaxf(0.f, fmaxf(__fsub_rn(bx0, qx), __fsub_rn(qx, bx1)));
    float dym = fmaxf(0.f, fmaxf(__fsub_rn(by0, qy), __fsub_rn(qy, by1)));
    float dzm = fmaxf(0.f, fmaxf(__fsub_rn(bz0, qz), __fsub_rn(qz, bz1)));
    float lb2 = dxm * dxm + dym * dym + dzm * dzm;
    // safe-skip: lb2*(1-1e-5) >= segmax => no md in cell can change (chain err ~1e-6)
    bool dirty = !(lb2 * 0.99999f >= sv);

    // ---- scan dirty cells of my wave; slim two-phase reduce per cell ----
    unsigned long long mask = __ballot(dirty);
    while (mask) {
      int cl = (int)__builtin_ctzll(mask); mask &= mask - 1;
      int st = __builtin_amdgcn_readlane(stR, cl);
      int en = __builtin_amdgcn_readlane(enR, cl);
      float bv = -2.0f; unsigned bp = 0xFFFFFFFFu;
      float bxl = 0.f, byl = 0.f, bzl = 0.f;
      for (int p0 = st; p0 < en; p0 += 64) {
        int p = p0 + lane;
        if (p < en) {
          float4 v = pk[p];
          float dx = __fsub_rn(v.x, qx);
          float dy = __fsub_rn(v.y, qy);
          float dz = __fsub_rn(v.z, qz);
          float d2 = fmaf(dz, dz, fmaf(dy, dy, __fmul_rn(dx, dx)));  // frozen chain
          float nm = fminf(md[p], d2);
          md[p] = nm;
          unsigned pkd = (((unsigned)__float_as_int(v.w)) << 16) | (unsigned)p;
          if (nm > bv || (nm == bv && pkd < bp)) {
            bv = nm; bp = pkd; bxl = v.x; byl = v.y; bzl = v.z;
          }
        }
      }
      // two-phase: value max -> masked pkd min -> winner lane -> coord readlanes
      float mv = bv;
      DPP_MAXF_64(mv)
      float rmax = __int_as_float(__builtin_amdgcn_readlane(__float_as_int(mv), 63));
      unsigned mp = (bv == rmax) ? bp : 0xFFFFFFFFu;
      DPP_MINU_64(mp)
      unsigned rpkd = (unsigned)__builtin_amdgcn_readlane((int)mp, 63);
      unsigned long long wm = __ballot(bv == rmax && bp == rpkd);
      int wl = (int)__builtin_ctzll(wm);
      float wx = __int_as_float(__builtin_amdgcn_readlane(__float_as_int(bxl), wl));
      float wy = __int_as_float(__builtin_amdgcn_readlane(__float_as_int(byl), wl));
      float wz = __int_as_float(__builtin_amdgcn_readlane(__float_as_int(bzl), wl));
      if (lane == cl) {  // owner lane caches new seg state
        sv = rmax; spk = rpkd; sx = wx; sy = wy; sz = wz;
      }
    }

    // ---- wave candidate: slim two-phase over per-lane seg state ----
    {
      float cv = nonempty ? sv : -1.0f;
      unsigned cp = spk;
      float mv = cv;
      DPP_MAXF_64(mv)
      float rmax = __int_as_float(__builtin_amdgcn_readlane(__float_as_int(mv), 63));
      unsigned mp = (cv == rmax) ? cp : 0xFFFFFFFFu;
      DPP_MINU_64(mp)
      unsigned rpkd = (unsigned)__builtin_amdgcn_readlane((int)mp, 63);
      unsigned long long wm = __ballot(cv == rmax && cp == rpkd);
      int wl = (int)__builtin_ctzll(wm);
      float wx = __int_as_float(__builtin_amdgcn_readlane(__float_as_int(sx), wl));
      float wy = __int_as_float(__builtin_amdgcn_readlane(__float_as_int(sy), wl));
      float wz = __int_as_float(__builtin_amdgcn_readlane(__float_as_int(sz), wl));
      if (lane == 63) {
        unsigned* slot = &wc[((it & 1) << 6) + (w << 3)];
        slot[0] = (rmax < 0.f) ? 0u : __float_as_uint(rmax);  // empty wave -> key 0
        slot[1] = ~rpkd;
        slot[2] = __float_as_uint(wx); slot[3] = __float_as_uint(wy); slot[4] = __float_as_uint(wz);
      }
    }
    HOT_BARRIER()

    // ---- all waves: fold 8 slots (lanes 0..7), 3 DPP5 steps, winner in lane 7 ----
    {
      unsigned gh = 0u, gl = 0u; float gx = 0.f, gy = 0.f, gz = 0.f;
      if (lane < 8) {
        unsigned* slot = &wc[((it & 1) << 6) + (lane << 3)];
        gh = slot[0]; gl = slot[1];
        gx = __uint_as_float(slot[2]); gy = __uint_as_float(slot[3]); gz = __uint_as_float(slot[4]);
      }
      DPP5_STEP(gh, gl, gx, gy, gz, ROW_SHR1)
      DPP5_STEP(gh, gl, gx, gy, gz, ROW_SHR2)
      DPP5_STEP(gh, gl, gx, gy, gz, ROW_SHR4)
      qx = __int_as_float(__builtin_amdgcn_readlane(__float_as_int(gx), 7));
      qy = __int_as_float(__builtin_amdgcn_readlane(__float_as_int(gy), 7));
      qz = __int_as_float(__builtin_amdgcn_readlane(__float_as_int(gz), 7));
    }
    if (t == 0) {
      int s0 = (it & 511) * 3;
      winbuf[s0 + 0] = qx; winbuf[s0 + 1] = qy; winbuf[s0 + 2] = qz;
    }

    // ---- flush p2 every 512 iterations (global stores off the hot path) ----
    if ((it & 511) == 511) {
      __syncthreads();
      int j = it - 511 + t;
      if (j >= 1 && j <= it) {
        int s0 = (j & 511) * 3;
        p2[(size_t)j * 3 + 0] = winbuf[s0 + 0];
        p2[(size_t)j * 3 + 1] = winbuf[s0 + 1];
        p2[(size_t)j * 3 + 2] = winbuf[s0 + 2];
      }
      __syncthreads();
    }
  }
}

// ---------------- K4: 16-NN — expanded f32, all-FMA chains (frozen from R5) ----------------
__device__ __forceinline__ unsigned long long shfl_xor_u64(unsigned long long v, int m) {
  unsigned lo = __shfl_xor((unsigned)v, m);
  unsigned hi = __shfl_xor((unsigned)(v >> 32), m);
  return ((unsigned long long)hi << 32) | lo;
}

__global__ __launch_bounds__(256) void k_knn(const float* __restrict__ px,
                                             const float* __restrict__ py,
                                             const float* __restrict__ pz,
                                             const float* __restrict__ pp,
                                             const float* __restrict__ p2,
                                             int* __restrict__ nb) {
  __shared__ unsigned long long mq[4][16][64];
  int wid = threadIdx.x >> 6, lane = threadIdx.x & 63;
  int q = blockIdx.x * 4 + wid;
  float qx = p2[(size_t)q * 3 + 0], qy = p2[(size_t)q * 3 + 1], qz = p2[(size_t)q * 3 + 2];
  float qq = sq3_fma(qx, qy, qz);

  unsigned long long sl[16];
#pragma unroll
  for (int s = 0; s < 16; ++s) sl[s] = ~0ULL;

#pragma unroll 2
  for (int c = 0; c < 512; ++c) {
    int i = c * 64 + lane;
    float X = px[i], Y = py[i], Z = pz[i], P = pp[i];
    float dot = fmaf(qz, Z, fmaf(qy, Y, __fmul_rn(qx, X)));       // fma-ascending
    float d2 = __fadd_rn(__fsub_rn(qq, __fadd_rn(dot, dot)), P);  // (qq - 2*dot) + pp
    unsigned u = __float_as_uint(d2);
    u ^= ((unsigned)(((int)u) >> 31)) | 0x80000000u;
    unsigned long long key = ((unsigned long long)u << 32) | (unsigned)i;
#pragma unroll
    for (int s = 0; s < 16; ++s) {
      unsigned long long lo = key < sl[s] ? key : sl[s];
      unsigned long long hi = key < sl[s] ? sl[s] : key;
      sl[s] = lo;
      key = hi;
    }
  }
#pragma unroll
  for (int s = 0; s < 16; ++s) mq[wid][s][lane] = sl[s];
  int head = 0;
  for (int r = 0; r < 16; ++r) {
    int hh = head < 16 ? head : 15;
    unsigned long long kk = mq[wid][hh][lane];
    if (head >= 16) kk = ~0ULL;
    unsigned long long v = kk;
#pragma unroll
    for (int off = 32; off; off >>= 1) {
      unsigned long long o = shfl_xor_u64(v, off);
      if (o < v) v = o;
    }
    if (kk == v) head++;
    if (lane == 0) nb[(size_t)q * 16 + r] = (int)(v & 0xffffffffULL);
  }
}

// ---------------- K5: gather + affine + relu + maxpool ----------------
__global__ __launch_bounds__(256) void k_gather(const float* __restrict__ h,
                                                const float* __restrict__ ss,
                                                const int* __restrict__ nb,
                                                float* __restrict__ y) {
  int t = threadIdx.x;
  int q = blockIdx.x * 2 + (t >> 7);
  int ch = t & 127;
  float sc = ss[ch], sh = ss[128 + ch];
  float m = -3.4e38f;
#pragma unroll
  for (int k = 0; k < 16; ++k) {
    int n = nb[(size_t)q * 16 + k];
    float v = h[(size_t)n * 128 + ch];
    m = fmaxf(m, fmaf(v, sc, sh));
  }
  y[(size_t)q * 128 + ch] = fmaxf(m, 0.0f);
}

extern "C" void kernel_launch(void* const* d_in, const int* in_sizes, int n_in,
                              void* d_out, int out_size, void* d_ws, size_t ws_size,
                              hipStream_t stream) {
  (void)in_sizes; (void)n_in; (void)out_size; (void)ws_size;
  const float* x = (const float*)d_in[0];
  const float* p1 = (const float*)d_in[1];
  const float* W = (const float*)d_in[2];
  const float* bias = (const float*)d_in[3];
  const float* gamma = (const float*)d_in[4];
  const float* beta = (const float*)d_in[5];

  float* out = (float*)d_out;
  float* y = out;                    // (8192,128)
  float* p2 = out + 1048576;         // (8192,3)

  // ws layout — identical footprint to R6/R8-proven:
  float* w = (float*)d_ws;
  float* h = w;                      // 4194304
  float* part = w + 4194304;         // 131072
  float* ss = w + 4325376;           // 256
  float* px = w + 4325632;           // 32768
  float* py = w + 4358400;
  float* pz = w + 4391168;
  float* pp = w + 4423936;
  int* nb = (int*)(w + 4456704);     // 8192*16 ints -> end 4489472 floats

  // FPS scratch in d_out's y-region (overwritten by k_gather at the very end):
  float4* pk = (float4*)y;           // 32768 float4 = 131072 floats
  int* cstart = (int*)(y + 131072);  // 513
  int* cursor = (int*)(y + 131648);  // 512   (end 132160 << 1048576)

  // md 32768 + wc 128 + winbuf 1536 = 34432 floats = 137728 B
  const int fps_lds = 34432 * 4;
  hipFuncSetAttribute((const void*)k_fps11, hipFuncAttributeMaxDynamicSharedMemorySize, fps_lds);

  k_soa<<<128, 256, 0, stream>>>(p1, px, py, pz, pp);
  k_cells<<<1, 1024, 0, stream>>>(px, py, pz, cstart, cursor);
  k_scatter<<<128, 256, 0, stream>>>(px, py, pz, cursor, pk);
  k_mlp<<<512, 256, 0, stream>>>(x, W, bias, h, part);
  k_bn<<<1, 128, 0, stream>>>(part, gamma, beta, ss);
  k_fps11<<<1, 512, fps_lds, stream>>>(pk, cstart, p1, p2);
  k_knn<<<2048, 256, 0, stream>>>(px, py, pz, pp, p2, nb);
  k_gather<<<4096, 256, 0, stream>>>(h, ss, nb, y);
}